// Round 6
// baseline (238.819 us; speedup 1.0000x reference)
//
#include <hip/hip_runtime.h>

// CovarianceLayer: x [B=64, C=4, T=8192, M=16] fp32 -> cov [B, C, 16, 16] fp32
// cov = (P - S S^T / T) / (T-1),  P = X^T X via mfma_f32_16x16x32_bf16.
//
// R15 = DIAGNOSTIC PROBE ROUND. R10 base, verbatim, plus 6 extra NT probe
// loads per lane per round from the workspace (read-and-discard, kept live
// via asm sink). Purpose: the cov kernel has NEVER appeared in the rocprof
// top-5 (all rows are ~78us 512MiB harness fills -> kernel < 77us), so its
// achieved read BW is unknown. Two models fit all data so far:
//   A) dur_us = 2 fills (~156us) + kernel ~22us  -> R10 already at the
//      134MB/6.3TB/s read floor; nothing left to win in-kernel.
//   B) dur_us = 1 fill + overhead + kernel ~77us (~1.74TB/s) -> 3.5x
//      headroom behind a chip-level read pin.
// The probe quadruples the dispatch's read volume (~536MB) so it outruns
// the 80us fills and surfaces in top-5 WITH counters: hbm_gbps of that row
// is the direct measurement this session has been missing.
//   Case A: hbm_gbps >= 5500, dur_us 235-255 -> resubmit R10, ROOFLINE.
//   Case B: hbm_gbps 1800-2800, dur_us 350-480 -> VALUBusy/Occupancy of the
//           row identify the binder; attack it on the R10 base.
//
// Probe design: per (block, round, wave, k) one contiguous 1KB slab of ws
// (coalesced); blocks cover disjoint 1.5MiB regions, wrapping at 256MiB.
// ws was just poison-filled (512MiB write) so it is fill-swept, not
// LLC-resident. Integer accumulate of all 4 components (prevents load
// narrowing), single asm-volatile sink after the loop (prevents DCE).
// If ws is too small, falls back to probing x itself (128MiB mask).
//
// R10 structure (unchanged): per 32-row round, 2 coalesced NT float4
// loads/lane (rows rg, rg+16 -- contiguous per instr), fp32 column sums,
// bf16 pack, swizzled wave-private LDS transpose, 1 MFMA (A==B fragment).
// No barriers in main loop; block combine + finalize as before.

constexpr int T_DIM = 8192;
constexpr int M_DIM = 16;
constexpr int BLOCK = 1024;                 // 16 waves, 1 block per (b,c)
constexpr int NWAVE = BLOCK / 64;           // 16
constexpr int T_PER_WAVE = T_DIM / NWAVE;   // 512 rows
constexpr int ROUNDS = T_PER_WAVE / 32;     // 16 rounds of 32 rows
constexpr int PF = 4;                       // prefetch depth
constexpr int NPROBE = 6;                   // probe loads per lane per round

using bf16x8 = __attribute__((ext_vector_type(8))) short;
using f32x4  = __attribute__((ext_vector_type(4))) float;
using i32x4  = __attribute__((ext_vector_type(4))) int;

static __device__ inline unsigned pack_bf2(float lo, float hi) {
    union { float f; unsigned u; } a{lo}, b{hi};
    unsigned ra = a.u + 0x7fffu + ((a.u >> 16) & 1u);
    unsigned rb = b.u + 0x7fffu + ((b.u >> 16) & 1u);
    return (ra >> 16) | (rb & 0xffff0000u);
}

__global__ __launch_bounds__(BLOCK)
void cov_kernel(const float* __restrict__ x, float* __restrict__ out,
                const i32x4* __restrict__ pbase, unsigned pmask) {
    const int bc   = blockIdx.x;
    const int tid  = threadIdx.x;
    const int wave = tid >> 6;
    const int lane = tid & 63;

    const int rg = lane >> 2;
    const int g  = lane & 3;
    const int q  = lane >> 4;
    const int m  = lane & 15;

    __shared__ __align__(16) unsigned stage[NWAVE][2][256];
    __shared__ float Pred[NWAVE][256];
    __shared__ float Sred[NWAVE][M_DIM];
    __shared__ float Stot[M_DIM];

    const f32x4* __restrict__ xin =
        (const f32x4*)(x + (size_t)bc * (T_DIM * M_DIM));

    const int idx0 = wave * (T_PER_WAVE * 4) + lane;

    const int qw = rg >> 2, dq = rg & 3;
    const int roff = (q * 16 + (m ^ q)) * 4;

    // Probe base f4 index: block covers [bc*ROUNDS*NWAVE*NPROBE*64, +1.5MiB)
    const unsigned pidx0 =
        ((unsigned)bc * ROUNDS * NWAVE * NPROBE + (unsigned)wave * NPROBE) * 64u
        + (unsigned)lane;
    int psum = 0;

    f32x4 acc = {0.f, 0.f, 0.f, 0.f};
    float s0 = 0.f, s1 = 0.f, s2 = 0.f, s3 = 0.f;

    f32x4 buf0[PF], buf1[PF];
#pragma unroll
    for (int r = 0; r < PF; ++r) {
        buf0[r] = __builtin_nontemporal_load(&xin[idx0 + r * 128]);
        buf1[r] = __builtin_nontemporal_load(&xin[idx0 + r * 128 + 64]);
    }

#pragma unroll
    for (int r = 0; r < ROUNDS; ++r) {
        const f32x4 a0 = buf0[r % PF];   // row rg      , cols 4g..4g+3
        const f32x4 a1 = buf1[r % PF];   // row rg + 16 , cols 4g..4g+3
        if (r + PF < ROUNDS) {
            buf0[r % PF] =
                __builtin_nontemporal_load(&xin[idx0 + (r + PF) * 128]);
            buf1[r % PF] =
                __builtin_nontemporal_load(&xin[idx0 + (r + PF) * 128 + 64]);
        }

        // ---- diagnostic probe: NPROBE x 16B NT reads, discarded ----
        {
            const unsigned pr = pidx0 + (unsigned)r * (NWAVE * NPROBE * 64);
#pragma unroll
            for (int k = 0; k < NPROBE; ++k) {
                i32x4 p = __builtin_nontemporal_load(
                    &pbase[(pr + (unsigned)k * 64u) & pmask]);
                psum += (p[0] + p[1]) + (p[2] + p[3]);
            }
        }
        // ------------------------------------------------------------

        s0 += a0[0] + a1[0];  s1 += a0[1] + a1[1];
        s2 += a0[2] + a1[2];  s3 += a0[3] + a1[3];
        unsigned* wb = &stage[wave][r & 1][0];
        wb[(qw * 16 + ((4 * g + 0) ^ qw)) * 4 + dq] = pack_bf2(a0[0], a1[0]);
        wb[(qw * 16 + ((4 * g + 1) ^ qw)) * 4 + dq] = pack_bf2(a0[1], a1[1]);
        wb[(qw * 16 + ((4 * g + 2) ^ qw)) * 4 + dq] = pack_bf2(a0[2], a1[2]);
        wb[(qw * 16 + ((4 * g + 3) ^ qw)) * 4 + dq] = pack_bf2(a0[3], a1[3]);
        bf16x8 frag = *(const bf16x8*)&stage[wave][r & 1][roff];
        acc = __builtin_amdgcn_mfma_f32_16x16x32_bf16(frag, frag, acc, 0, 0, 0);
    }

    // Keep the probe results architecturally live (no DCE), then discard.
    asm volatile("" :: "v"(psum));

#pragma unroll
    for (int off = 4; off <= 32; off <<= 1) {
        s0 += __shfl_xor(s0, off, 64);
        s1 += __shfl_xor(s1, off, 64);
        s2 += __shfl_xor(s2, off, 64);
        s3 += __shfl_xor(s3, off, 64);
    }
    if (rg == 0) {
        Sred[wave][4 * g + 0] = s0;
        Sred[wave][4 * g + 1] = s1;
        Sred[wave][4 * g + 2] = s2;
        Sred[wave][4 * g + 3] = s3;
    }

#pragma unroll
    for (int r = 0; r < 4; ++r)
        Pred[wave][(q * 4 + r) * M_DIM + m] = acc[r];
    __syncthreads();

    if (tid < M_DIM) {
        float s = 0.f;
#pragma unroll
        for (int w = 0; w < NWAVE; ++w) s += Sred[w][tid];
        Stot[tid] = s;
    }
    __syncthreads();

    if (tid < 256) {
        float P = 0.f;
#pragma unroll
        for (int w = 0; w < NWAVE; ++w) P += Pred[w][tid];
        const int mi = tid >> 4;
        const int ni = tid & 15;
        const float cov = (P - Stot[mi] * Stot[ni] * (1.0f / (float)T_DIM))
                        * (1.0f / (float)(T_DIM - 1));
        out[(size_t)bc * 256 + tid] = cov;
    }
}

extern "C" void kernel_launch(void* const* d_in, const int* in_sizes, int n_in,
                              void* d_out, int out_size, void* d_ws, size_t ws_size,
                              hipStream_t stream) {
    const float* x = (const float*)d_in[0];
    float* out = (float*)d_out;
    const int n_bc = in_sizes[0] / (T_DIM * M_DIM);   // B*C = 256

    // Probe target: workspace if it holds >= 256MiB (mask 2^24 f4 = 256MiB,
    // fill-swept so not LLC-resident); else fall back to x (128MiB mask).
    const void* pb;
    unsigned pmask;
    if (ws_size >= (1ull << 28)) {
        pb = d_ws;            pmask = (1u << 24) - 1u;
    } else {
        pb = (const void*)x;  pmask = (1u << 23) - 1u;
    }
    cov_kernel<<<dim3(n_bc), dim3(BLOCK), 0, stream>>>(
        x, out, (const i32x4*)pb, pmask);
}

// Round 7
// 177.794 us; speedup vs baseline: 1.3432x; 1.3432x over previous
//
#include <hip/hip_runtime.h>

// CovarianceLayer: x [B=64, C=4, T=8192, M=16] fp32 -> cov [B, C, 16, 16] fp32
// cov = (P - S S^T / T) / (T-1),  P = X^T X via mfma_f32_16x16x32_bf16.
//
// R16 = OCCUPANCY EXPERIMENT on the R10 consumer (one mechanistic variable).
//
// R15 probe round resolved the accounting (first cov_kernel counter rows):
//   probe dispatch 91us, FETCH 268MB -> 2.95 TB/s aggregate, VALUBusy 7%,
//   MfmaUtil 0.4%, Occupancy ~40% (static 50%: 256 blocks x 1024 = exactly
//   1 block/CU), VGPR 56. Fixed harness pedestal = 238.8-91 = ~148us ->
//   R10 kernel = 177.8-148 = ~30us = 4.5 TB/s pure read. Headroom to a
//   6.3 TB/s read floor: 30 -> 21.3us (dur_us -> ~169).
//
// Hypothesis under test: request supply. R10 runs 16 waves/CU with ~8
// outstanding 16B loads each; everything else in the counter row is idle.
// R16 doubles static occupancy to 32 waves/CU (100%): 8 T-segments per
// (b,c), grid1 = 2048 blocks x 256 threads (4 waves; per-wave loop
// IDENTICAL to R10: 32-row rounds, PF=4, NT loads, pack->LDS swizzle->
// MFMA A==B). LDS 12.3KB, VGPR 56 -> 8 blocks/CU. Partials (256 P + 16 S
// per block) go to ws; kernel2 (256 x 256) finalizes (~3us, 2.2MB traffic).
//
// Pre-committed: dur_us <= 172 confirms occupancy was the binder;
// 178-186 = null -> R7 logic holds (pattern ceiling ~4.5 TB/s), resubmit
// R10 and declare ROOFLINE. Counter row (if kernel1 surfaces): Occupancy
// ~80%+, hbm_gbps up.

constexpr int T_DIM = 8192;
constexpr int M_DIM = 16;
constexpr int NSEG  = 8;                     // T-segments per (b,c)
constexpr int T_SEG = T_DIM / NSEG;          // 1024 rows
constexpr int BLOCK1 = 256;                  // 4 waves
constexpr int NWAVE1 = BLOCK1 / 64;          // 4
constexpr int T_PER_WAVE = T_SEG / NWAVE1;   // 256 rows
constexpr int ROUNDS = T_PER_WAVE / 32;      // 8 rounds of 32 rows
constexpr int PF = 4;                        // prefetch depth
constexpr int WS_STRIDE = 272;               // 256 P + 16 S floats per block

using bf16x8 = __attribute__((ext_vector_type(8))) short;
using f32x4  = __attribute__((ext_vector_type(4))) float;

static __device__ inline unsigned pack_bf2(float lo, float hi) {
    // RNE fp32->bf16 for both, packed lo | hi<<16 (finite normal inputs)
    union { float f; unsigned u; } a{lo}, b{hi};
    unsigned ra = a.u + 0x7fffu + ((a.u >> 16) & 1u);
    unsigned rb = b.u + 0x7fffu + ((b.u >> 16) & 1u);
    return (ra >> 16) | (rb & 0xffff0000u);
}

__global__ __launch_bounds__(BLOCK1, 8)
void cov_partial(const float* __restrict__ x, float* __restrict__ ws) {
    const int blk  = blockIdx.x;
    const int bc   = blk >> 3;               // blk / NSEG
    const int seg  = blk & (NSEG - 1);
    const int tid  = threadIdx.x;
    const int wave = tid >> 6;
    const int lane = tid & 63;

    // staging roles (as R10): lane covers rows rg, rg+16 (round-local),
    // cols 4g..4g+3; loads are base+lane, base+lane+64 -- contiguous/instr.
    const int rg = lane >> 2;
    const int g  = lane & 3;
    // MFMA roles: col = m, k-rows q*8..q*8+7
    const int q  = lane >> 4;
    const int m  = lane & 15;

    __shared__ __align__(16) unsigned stage[NWAVE1][2][256];  // 2x1KB/wave
    __shared__ float Pred[NWAVE1][256];
    __shared__ float Sred[NWAVE1][M_DIM];

    const f32x4* __restrict__ xin =
        (const f32x4*)(x + ((size_t)bc * T_DIM + (size_t)seg * T_SEG) * M_DIM);

    // float4 index; round stride = 32 rows = 128 f4. Wave covers 256 rows.
    const int idx0 = wave * (T_PER_WAVE * 4) + lane;

    const int qw = rg >> 2, dq = rg & 3;
    const int roff = (q * 16 + (m ^ q)) * 4;

    f32x4 acc = {0.f, 0.f, 0.f, 0.f};
    float s0 = 0.f, s1 = 0.f, s2 = 0.f, s3 = 0.f;

    f32x4 buf0[PF], buf1[PF];
#pragma unroll
    for (int r = 0; r < PF; ++r) {
        buf0[r] = __builtin_nontemporal_load(&xin[idx0 + r * 128]);
        buf1[r] = __builtin_nontemporal_load(&xin[idx0 + r * 128 + 64]);
    }

#pragma unroll
    for (int r = 0; r < ROUNDS; ++r) {
        const f32x4 a0 = buf0[r % PF];   // row rg      , cols 4g..4g+3
        const f32x4 a1 = buf1[r % PF];   // row rg + 16 , cols 4g..4g+3
        if (r + PF < ROUNDS) {
            buf0[r % PF] =
                __builtin_nontemporal_load(&xin[idx0 + (r + PF) * 128]);
            buf1[r % PF] =
                __builtin_nontemporal_load(&xin[idx0 + (r + PF) * 128 + 64]);
        }

        s0 += a0[0] + a1[0];  s1 += a0[1] + a1[1];
        s2 += a0[2] + a1[2];  s3 += a0[3] + a1[3];
        unsigned* wb = &stage[wave][r & 1][0];
        wb[(qw * 16 + ((4 * g + 0) ^ qw)) * 4 + dq] = pack_bf2(a0[0], a1[0]);
        wb[(qw * 16 + ((4 * g + 1) ^ qw)) * 4 + dq] = pack_bf2(a0[1], a1[1]);
        wb[(qw * 16 + ((4 * g + 2) ^ qw)) * 4 + dq] = pack_bf2(a0[2], a1[2]);
        wb[(qw * 16 + ((4 * g + 3) ^ qw)) * 4 + dq] = pack_bf2(a0[3], a1[3]);
        bf16x8 frag = *(const bf16x8*)&stage[wave][r & 1][roff];
        acc = __builtin_amdgcn_mfma_f32_16x16x32_bf16(frag, frag, acc, 0, 0, 0);
    }

    // Wave column sums: reduce over rg (lane bits 2..5); lanes 0..3 hold
    // cols 4g..4g+3.
#pragma unroll
    for (int off = 4; off <= 32; off <<= 1) {
        s0 += __shfl_xor(s0, off, 64);
        s1 += __shfl_xor(s1, off, 64);
        s2 += __shfl_xor(s2, off, 64);
        s3 += __shfl_xor(s3, off, 64);
    }
    if (rg == 0) {
        Sred[wave][4 * g + 0] = s0;
        Sred[wave][4 * g + 1] = s1;
        Sred[wave][4 * g + 2] = s2;
        Sred[wave][4 * g + 3] = s3;
    }

    // Per-wave partial P into LDS. C/D layout: col = m, row = q*4 + reg.
#pragma unroll
    for (int r = 0; r < 4; ++r)
        Pred[wave][(q * 4 + r) * M_DIM + m] = acc[r];
    __syncthreads();

    // Block combine -> ws partials (fp32).
    {
        float P = 0.f;
#pragma unroll
        for (int w = 0; w < NWAVE1; ++w) P += Pred[w][tid];
        ws[(size_t)blk * WS_STRIDE + tid] = P;
    }
    if (tid < M_DIM) {
        float s = 0.f;
#pragma unroll
        for (int w = 0; w < NWAVE1; ++w) s += Sred[w][tid];
        ws[(size_t)blk * WS_STRIDE + 256 + tid] = s;
    }
}

__global__ __launch_bounds__(256)
void cov_final(const float* __restrict__ ws, float* __restrict__ out) {
    const int bc  = blockIdx.x;
    const int tid = threadIdx.x;
    __shared__ float Stot[M_DIM];

    if (tid < M_DIM) {
        float s = 0.f;
#pragma unroll
        for (int q = 0; q < NSEG; ++q)
            s += ws[((size_t)bc * NSEG + q) * WS_STRIDE + 256 + tid];
        Stot[tid] = s;
    }
    __syncthreads();

    float P = 0.f;
#pragma unroll
    for (int q = 0; q < NSEG; ++q)
        P += ws[((size_t)bc * NSEG + q) * WS_STRIDE + tid];

    const int mi = tid >> 4;
    const int ni = tid & 15;
    const float cov = (P - Stot[mi] * Stot[ni] * (1.0f / (float)T_DIM))
                    * (1.0f / (float)(T_DIM - 1));
    out[(size_t)bc * 256 + tid] = cov;
}

extern "C" void kernel_launch(void* const* d_in, const int* in_sizes, int n_in,
                              void* d_out, int out_size, void* d_ws, size_t ws_size,
                              hipStream_t stream) {
    const float* x = (const float*)d_in[0];
    float* out = (float*)d_out;
    float* ws  = (float*)d_ws;
    const int n_bc = in_sizes[0] / (T_DIM * M_DIM);   // B*C = 256
    cov_partial<<<dim3(n_bc * NSEG), dim3(BLOCK1), 0, stream>>>(x, ws);
    cov_final<<<dim3(n_bc), dim3(256), 0, stream>>>(ws, out);
}